// Round 4
// baseline (128.369 us; speedup 1.0000x reference)
//
#include <hip/hip_runtime.h>
#include <hip/hip_bf16.h>

// Problem constants (from setup_inputs): B=8, N=M=4096, 3D points, fp32.
constexpr int B_ = 8;
constexpr int N_ = 4096;
constexpr int M_ = 4096;
constexpr int TPB = 256;          // 4 waves/block
constexpr int QPB = TPB / 2;      // 128 queries per block (2 threads/query)
constexpr int QBLKS = N_ / QPB;   // 32 query-blocks per batch
constexpr int HALF = M_ / 2;      // each thread scans half the database

// ---------------------------------------------------------------------------
// Fused chamfer: one kernel, no atomics, no workspace init.
// Block = (dir, batch, 128 queries). The full 4096-point database of batch b
// is staged once into 64 KB LDS, pre-scaled as (-2x,-2y,-2z,||y||^2) so each
// pair costs 3 FMA + 1 min. Threads 2t,2t+1 share query t: even lanes scan
// points [0,2048), odd lanes [2048,4096) -> per-wave LDS reads hit only 2
// distinct addresses (free broadcast). Partner min via __shfl_xor, then
// fused sqrt + deterministic block tree-sum -> one partial per block.
// Grid 512 = 2 blocks/CU (2x64KB LDS fits in 160KB), 8 waves/CU.
// ---------------------------------------------------------------------------
__global__ __launch_bounds__(TPB) void chamfer_fused(
    const float* __restrict__ X, const float* __restrict__ Yp,
    float* __restrict__ partial)
{
    __shared__ float4 sdb[M_];     // 64 KB
    __shared__ float wsum[TPB / 64];

    int bid = blockIdx.x;
    const int dir  = bid & 1;              bid >>= 1;
    const int qblk = bid & (QBLKS - 1);    bid >>= 5;
    const int b    = bid;                  // 0..7

    const float* q  = dir ? Yp : X;
    const float* db = dir ? X  : Yp;

    // Stage full database for this batch, pre-scaled.
    const int dbbase = b * M_;
    for (int p = threadIdx.x; p < M_; p += TPB) {
        const float* src = db + (size_t)(dbbase + p) * 3;
        float a0 = src[0], a1 = src[1], a2 = src[2];
        sdb[p] = make_float4(-2.0f * a0, -2.0f * a1, -2.0f * a2,
                             a0 * a0 + a1 * a1 + a2 * a2);
    }

    // Load this thread's query before the barrier (overlaps staging).
    const int qi = qblk * QPB + (threadIdx.x >> 1);
    const float* qp = q + (size_t)(b * N_ + qi) * 3;
    const float ax = qp[0], ay = qp[1], az = qp[2];
    const float an = ax * ax + ay * ay + az * az;
    __syncthreads();

    const float4* pbase = sdb + (threadIdx.x & 1) * HALF;
    const float BIG = 3.0e38f;
    float m0 = BIG, m1 = BIG, m2 = BIG, m3 = BIG;
    #pragma unroll 2
    for (int j = 0; j < HALF; j += 4) {
        float4 p0 = pbase[j + 0];
        float4 p1 = pbase[j + 1];
        float4 p2 = pbase[j + 2];
        float4 p3 = pbase[j + 3];
        m0 = fminf(m0, fmaf(ax, p0.x, fmaf(ay, p0.y, fmaf(az, p0.z, p0.w))));
        m1 = fminf(m1, fmaf(ax, p1.x, fmaf(ay, p1.y, fmaf(az, p1.z, p1.w))));
        m2 = fminf(m2, fmaf(ax, p2.x, fmaf(ay, p2.y, fmaf(az, p2.z, p2.w))));
        m3 = fminf(m3, fmaf(ax, p3.x, fmaf(ay, p3.y, fmaf(az, p3.z, p3.w))));
    }
    float m = fminf(fminf(m0, m1), fminf(m2, m3));
    m = fminf(m, __shfl_xor(m, 1, 64));                 // combine the 2 halves
    float d = (threadIdx.x & 1) ? 0.0f : sqrtf(fmaxf(m + an, 0.0f));

    // Deterministic block tree-sum (odd lanes contribute 0).
    #pragma unroll
    for (int off = 32; off > 0; off >>= 1) d += __shfl_down(d, off, 64);
    if ((threadIdx.x & 63) == 0) wsum[threadIdx.x >> 6] = d;
    __syncthreads();
    if (threadIdx.x == 0)
        partial[blockIdx.x] = wsum[0] + wsum[1] + wsum[2] + wsum[3];
}

// ---------------------------------------------------------------------------
// Final: sum the 512 block partials, compute registration loss (8 batches on
// threads 0..7), write (total, L_R, L_CD).
// ---------------------------------------------------------------------------
__global__ __launch_bounds__(512) void final_kernel(
    const float* __restrict__ partial,          // 512 entries
    const float* __restrict__ R,  const float* __restrict__ t,
    const float* __restrict__ S,  const float* __restrict__ Rg,
    const float* __restrict__ tg, const float* __restrict__ Sg,
    float* __restrict__ out)
{
    __shared__ float wsum[8];
    __shared__ float sreg[8];
    const int tid = threadIdx.x;

    float s = partial[tid];
    #pragma unroll
    for (int off = 32; off > 0; off >>= 1) s += __shfl_down(s, off, 64);
    if ((tid & 63) == 0) wsum[tid >> 6] = s;

    if (tid < 8) {
        const float* Rb  = R  + tid * 9;
        const float* Rgb = Rg + tid * 9;
        float acc = 0.0f;
        #pragma unroll
        for (int i = 0; i < 3; ++i) {
            #pragma unroll
            for (int k = 0; k < 3; ++k) {
                float v = 0.0f;
                #pragma unroll
                for (int j = 0; j < 3; ++j)
                    v = fmaf(Rgb[j * 3 + i], Rb[j * 3 + k], v);  // (R_g^T R)[i][k]
                if (i == k) v -= 1.0f;
                acc = fmaf(v, v, acc);
            }
        }
        #pragma unroll
        for (int d = 0; d < 3; ++d) {
            float dv = tg[tid * 3 + d] - t[tid * 3 + d];
            acc = fmaf(dv, dv, acc);
        }
        float dS = Sg[tid] - S[tid];
        acc = fmaf(dS, dS, acc);
        sreg[tid] = acc;
    }
    __syncthreads();

    if (tid == 0) {
        float tot = 0.0f;
        #pragma unroll
        for (int w = 0; w < 8; ++w) tot += wsum[w];
        float L_CD = tot / (float)(B_ * N_);   // sum/(B*N) + sum/(B*M), N==M
        float rs = 0.0f;
        #pragma unroll
        for (int bb = 0; bb < 8; ++bb) rs += sreg[bb];
        float L_R = rs / (float)B_;
        out[0] = L_R + L_CD;
        out[1] = L_R;
        out[2] = L_CD;
    }
}

extern "C" void kernel_launch(void* const* d_in, const int* in_sizes, int n_in,
                              void* d_out, int out_size, void* d_ws, size_t ws_size,
                              hipStream_t stream) {
    const float* R  = (const float*)d_in[0];
    const float* t  = (const float*)d_in[1];
    const float* S  = (const float*)d_in[2];
    const float* Rg = (const float*)d_in[3];
    const float* tg = (const float*)d_in[4];
    const float* Sg = (const float*)d_in[5];
    const float* X  = (const float*)d_in[6];   // T_X [B,N,3]
    const float* Yp = (const float*)d_in[7];   // Y   [B,M,3]
    float* out = (float*)d_out;

    float* partial = (float*)d_ws;             // 512 floats, fully overwritten

    chamfer_fused<<<2 * B_ * QBLKS, TPB, 0, stream>>>(X, Yp, partial);
    final_kernel<<<1, 512, 0, stream>>>(partial, R, t, S, Rg, tg, Sg, out);
}

// Round 5
// 92.081 us; speedup vs baseline: 1.3941x; 1.3941x over previous
//
#include <hip/hip_runtime.h>
#include <hip/hip_bf16.h>

// Problem constants (from setup_inputs): B=8, N=M=4096, 3D points, fp32.
constexpr int B_ = 8;
constexpr int N_ = 4096;
constexpr int M_ = 4096;
constexpr int TPB = 256;            // 4 waves/block
constexpr int QPT = 4;              // queries per thread, in registers
constexpr int QPB = TPB * QPT;      // 1024 queries per block
constexpr int QBLKS = N_ / QPB;     // 4 query-blocks per batch
constexpr int SPLIT = 16;           // db chunks
constexpr int CHUNK = M_ / SPLIT;   // 256 db points staged in LDS (4 KB)
constexpr int NQ = 2 * B_ * N_;     // 65536 total queries (both directions)

// ---------------------------------------------------------------------------
// K1: block = (dir, batch, query-block, chunk). Stage 256 db points into LDS
// pre-scaled as (-2x,-2y,-2z,||y||^2); each pair = 3-FMA chain + 1 min.
// All 64 lanes read the SAME LDS address -> pure broadcast, zero conflicts.
// 4 queries/thread in registers -> 16 VALU ops per ds_read_b128.
// Each block writes 1024 per-query partial mins to a unique coalesced slot:
// part[chunk*NQ + qid]  (no atomics, no init needed).
// Grid = 1024 blocks = exactly 4 blocks/CU, one full round, 16 waves/CU.
// ---------------------------------------------------------------------------
__global__ __launch_bounds__(TPB) void chamfer_pass1(
    const float* __restrict__ X, const float* __restrict__ Yp,
    float* __restrict__ part)
{
    __shared__ float4 sdb[CHUNK];   // 4 KB

    int bid = blockIdx.x;
    const int dir   = bid & 1;             bid >>= 1;
    const int chunk = bid & (SPLIT - 1);   bid >>= 4;
    const int qblk  = bid & (QBLKS - 1);   bid >>= 2;
    const int b     = bid;                 // 0..7

    const float* q  = dir ? Yp : X;
    const float* db = dir ? X  : Yp;

    const int t = threadIdx.x;

    // Stage chunk (one point per thread; CHUNK == TPB).
    {
        const float* src = db + (size_t)(b * M_ + chunk * CHUNK + t) * 3;
        float a0 = src[0], a1 = src[1], a2 = src[2];
        sdb[t] = make_float4(-2.0f * a0, -2.0f * a1, -2.0f * a2,
                             a0 * a0 + a1 * a1 + a2 * a2);
    }

    // Load 4 queries into registers (overlaps staging, before barrier).
    float qx[QPT], qy[QPT], qz[QPT], qn[QPT];
    const int qbase = b * N_ + qblk * QPB;
    #pragma unroll
    for (int k = 0; k < QPT; ++k) {
        const float* qp = q + (size_t)(qbase + k * TPB + t) * 3;
        qx[k] = qp[0]; qy[k] = qp[1]; qz[k] = qp[2];
        qn[k] = qx[k] * qx[k] + qy[k] * qy[k] + qz[k] * qz[k];
    }
    __syncthreads();

    const float BIG = 3.0e38f;
    float mA[QPT], mB[QPT];
    #pragma unroll
    for (int k = 0; k < QPT; ++k) { mA[k] = BIG; mB[k] = BIG; }

    #pragma unroll 2
    for (int j = 0; j < CHUNK; j += 4) {
        float4 p0 = sdb[j + 0];
        float4 p1 = sdb[j + 1];
        float4 p2 = sdb[j + 2];
        float4 p3 = sdb[j + 3];
        #pragma unroll
        for (int k = 0; k < QPT; ++k) {
            mA[k] = fminf(mA[k], fmaf(qx[k], p0.x, fmaf(qy[k], p0.y, fmaf(qz[k], p0.z, p0.w))));
            mB[k] = fminf(mB[k], fmaf(qx[k], p1.x, fmaf(qy[k], p1.y, fmaf(qz[k], p1.z, p1.w))));
            mA[k] = fminf(mA[k], fmaf(qx[k], p2.x, fmaf(qy[k], p2.y, fmaf(qz[k], p2.z, p2.w))));
            mB[k] = fminf(mB[k], fmaf(qx[k], p3.x, fmaf(qy[k], p3.y, fmaf(qz[k], p3.z, p3.w))));
        }
    }

    // One write per query: part[chunk][qid], qid globally unique -> no atomics.
    const int wbase = chunk * NQ + dir * (B_ * N_) + qbase;
    #pragma unroll
    for (int k = 0; k < QPT; ++k) {
        float d2 = fmaxf(fminf(mA[k], mB[k]) + qn[k], 0.0f);
        part[wbase + k * TPB + t] = d2;
    }
}

// ---------------------------------------------------------------------------
// K2: one thread per query. Min over the 16 chunk-partials (each load
// coalesced across the wave), sqrt, deterministic block tree-sum.
// ---------------------------------------------------------------------------
__global__ __launch_bounds__(TPB) void min_sqrt_sum(
    const float* __restrict__ part, float* __restrict__ bsum)
{
    __shared__ float wsum[TPB / 64];
    const int qid = blockIdx.x * TPB + threadIdx.x;

    float m = part[qid];
    #pragma unroll
    for (int c = 1; c < SPLIT; ++c) m = fminf(m, part[c * NQ + qid]);
    float d = sqrtf(m);

    #pragma unroll
    for (int off = 32; off > 0; off >>= 1) d += __shfl_down(d, off, 64);
    if ((threadIdx.x & 63) == 0) wsum[threadIdx.x >> 6] = d;
    __syncthreads();
    if (threadIdx.x == 0)
        bsum[blockIdx.x] = wsum[0] + wsum[1] + wsum[2] + wsum[3];
}

// ---------------------------------------------------------------------------
// K3: sum the 256 block partials, registration loss (threads 0..7), output.
// ---------------------------------------------------------------------------
__global__ __launch_bounds__(TPB) void final_kernel(
    const float* __restrict__ bsum,
    const float* __restrict__ R,  const float* __restrict__ t,
    const float* __restrict__ S,  const float* __restrict__ Rg,
    const float* __restrict__ tg, const float* __restrict__ Sg,
    float* __restrict__ out)
{
    __shared__ float wsum[4];
    __shared__ float sreg[8];
    const int tid = threadIdx.x;

    float s = bsum[tid];
    #pragma unroll
    for (int off = 32; off > 0; off >>= 1) s += __shfl_down(s, off, 64);
    if ((tid & 63) == 0) wsum[tid >> 6] = s;

    if (tid < 8) {
        const float* Rb  = R  + tid * 9;
        const float* Rgb = Rg + tid * 9;
        float acc = 0.0f;
        #pragma unroll
        for (int i = 0; i < 3; ++i) {
            #pragma unroll
            for (int k = 0; k < 3; ++k) {
                float v = 0.0f;
                #pragma unroll
                for (int j = 0; j < 3; ++j)
                    v = fmaf(Rgb[j * 3 + i], Rb[j * 3 + k], v);  // (R_g^T R)[i][k]
                if (i == k) v -= 1.0f;
                acc = fmaf(v, v, acc);
            }
        }
        #pragma unroll
        for (int d = 0; d < 3; ++d) {
            float dv = tg[tid * 3 + d] - t[tid * 3 + d];
            acc = fmaf(dv, dv, acc);
        }
        float dS = Sg[tid] - S[tid];
        acc = fmaf(dS, dS, acc);
        sreg[tid] = acc;
    }
    __syncthreads();

    if (tid == 0) {
        float tot = wsum[0] + wsum[1] + wsum[2] + wsum[3];
        float L_CD = tot / (float)(B_ * N_);   // sum/(B*N) + sum/(B*M), N==M
        float rs = 0.0f;
        #pragma unroll
        for (int bb = 0; bb < 8; ++bb) rs += sreg[bb];
        float L_R = rs / (float)B_;
        out[0] = L_R + L_CD;
        out[1] = L_R;
        out[2] = L_CD;
    }
}

extern "C" void kernel_launch(void* const* d_in, const int* in_sizes, int n_in,
                              void* d_out, int out_size, void* d_ws, size_t ws_size,
                              hipStream_t stream) {
    const float* R  = (const float*)d_in[0];
    const float* t  = (const float*)d_in[1];
    const float* S  = (const float*)d_in[2];
    const float* Rg = (const float*)d_in[3];
    const float* tg = (const float*)d_in[4];
    const float* Sg = (const float*)d_in[5];
    const float* X  = (const float*)d_in[6];   // T_X [B,N,3]
    const float* Yp = (const float*)d_in[7];   // Y   [B,M,3]
    float* out = (float*)d_out;

    float* part = (float*)d_ws;                     // SPLIT*NQ floats (4 MB)
    float* bsum = part + (size_t)SPLIT * NQ;        // 256 floats

    chamfer_pass1<<<2 * B_ * QBLKS * SPLIT, TPB, 0, stream>>>(X, Yp, part);
    min_sqrt_sum<<<NQ / TPB, TPB, 0, stream>>>(part, bsum);
    final_kernel<<<1, TPB, 0, stream>>>(bsum, R, t, S, Rg, tg, Sg, out);
}